// Round 1
// baseline (754.065 us; speedup 1.0000x reference)
//
#include <hip/hip_runtime.h>

#define HW 57600
#define BATCH 16

// workspace layout (float offsets)
#define L_OFF    0        // [2][16][16]  softmax denominators
#define AT_OFF   512      // [2][16][32][16]  A^T (folded q·Wk), [s][b][i][t]
#define CV_OFF   16896    // [2][16][16]  score constants (later minus ln L)
#define XM_OFF   17408    // [2][16][32][16]  pooled x means [s][b][i][t]
#define WVT_OFF  33792    // [2][32][16]  Wv transposed [s][i][t]

// ---- kernel 1a: adaptive-pool means over interior 4x4 blocks of 40x40 ----
__global__ void k1a_pool(const float* __restrict__ x1, const float* __restrict__ x2,
                         float* __restrict__ ws) {
  int task = blockIdx.x * 4 + (threadIdx.x >> 6);   // [0, 16384)
  int lane = threadIdx.x & 63;
  int t = task & 15, i = (task >> 4) & 31, b = (task >> 9) & 15, s = task >> 13;
  int bi = 1 + (t >> 2), bj = 1 + (t & 3);
  const float* xp = (s ? x2 : x1) + (size_t)(b * 32 + i) * HW + (40 * bi) * 240 + 40 * bj;
  float sum = 0.f;
  #pragma unroll
  for (int k = 0; k < 25; ++k) {
    int e = lane + 64 * k;
    int r = e / 40, c = e - r * 40;
    sum += xp[r * 240 + c];
  }
  #pragma unroll
  for (int off = 32; off; off >>= 1) sum += __shfl_down(sum, off);
  if (lane == 0) ws[XM_OFF + task] = sum * (1.0f / 1600.0f);
}

// ---- kernel 1b: q = Wq*xmean+bq ; fold A^T[i][t] = sum_c q[t][c]*Wk[c][i]; cv[t]=q·bk ----
__global__ void k1b_fold(float* __restrict__ ws,
                         const float* __restrict__ Wq1, const float* __restrict__ bq1,
                         const float* __restrict__ Wq2, const float* __restrict__ bq2,
                         const float* __restrict__ Wk1, const float* __restrict__ bk1,
                         const float* __restrict__ Wk2, const float* __restrict__ bk2,
                         const float* __restrict__ Wv1, const float* __restrict__ Wv2) {
  int s = blockIdx.x >> 4, b = blockIdx.x & 15;
  const float* Wq = s ? Wq2 : Wq1;
  const float* bq = s ? bq2 : bq1;
  const float* Wk = s ? Wk1 : Wk2;   // cross: stream1 scores use Wk2, stream2 use Wk1
  const float* bk = s ? bk1 : bk2;
  __shared__ float xm[32][16];
  __shared__ float qv[16][16];
  int tid = threadIdx.x;
  for (int e = tid; e < 512; e += 256)
    xm[e >> 4][e & 15] = ws[XM_OFF + (s * 16 + b) * 512 + e];
  __syncthreads();
  {
    int t = tid >> 4, c = tid & 15;
    float acc = bq[c];
    #pragma unroll
    for (int i = 0; i < 32; ++i) acc += Wq[c * 32 + i] * xm[i][t];
    qv[t][c] = acc;
  }
  __syncthreads();
  for (int e = tid; e < 512; e += 256) {
    int i = e >> 4, t = e & 15;
    float acc = 0.f;
    #pragma unroll
    for (int c = 0; c < 16; ++c) acc += qv[t][c] * Wk[c * 32 + i];
    ws[AT_OFF + (s * 16 + b) * 512 + i * 16 + t] = acc;
  }
  if (tid < 16) {
    float acc = 0.f;
    #pragma unroll
    for (int c = 0; c < 16; ++c) acc += qv[tid][c] * bk[c];
    ws[CV_OFF + (s * 16 + b) * 16 + tid] = acc;
  }
  if (b == 0) {  // stash Wv transposed once per stream
    const float* Wv = s ? Wv2 : Wv1;
    for (int e = tid; e < 512; e += 256) {
      int i = e >> 4, t = e & 15;
      ws[WVT_OFF + s * 512 + i * 16 + t] = Wv[t * 32 + i];
    }
  }
}

// ---- kernel 2: softmax denominators L[s][b][t] = sum_n exp(A^T·x_other + cv) ----
__global__ void k2_sumexp(const float* __restrict__ x1, const float* __restrict__ x2,
                          float* __restrict__ ws) {
  int slice = blockIdx.x >> 4;      // (s,b)
  int sub = blockIdx.x & 15;
  int s = slice >> 4, b = slice & 15;
  const float* At = ws + AT_OFF + slice * 512;
  const float* cv = ws + CV_OFF + slice * 16;
  const float* xo = (s ? x1 : x2) + (size_t)b * 32 * HW;   // cross stream
  float* Lp = ws + L_OFF + slice * 16;
  float La[16];
  #pragma unroll
  for (int t = 0; t < 16; ++t) La[t] = 0.f;
  for (int n = sub * 256 + (int)threadIdx.x; n < HW; n += 4096) {
    float sc[16];
    #pragma unroll
    for (int t = 0; t < 16; ++t) sc[t] = cv[t];
    #pragma unroll
    for (int i = 0; i < 32; ++i) {
      float xi = xo[(size_t)i * HW + n];
      #pragma unroll
      for (int t = 0; t < 16; ++t) sc[t] += At[i * 16 + t] * xi;
    }
    #pragma unroll
    for (int t = 0; t < 16; ++t) La[t] += __expf(sc[t]);
  }
  #pragma unroll
  for (int t = 0; t < 16; ++t) {
    float v = La[t];
    #pragma unroll
    for (int off = 32; off; off >>= 1) v += __shfl_down(v, off);
    if ((threadIdx.x & 63) == 0) atomicAdd(&Lp[t], v);
  }
}

// ---- kernel 2b: fold -ln(L) into score constants ----
__global__ void k2b_log(float* __restrict__ ws) {
  int e = threadIdx.x;  // 512 threads
  float L = ws[L_OFF + e];
  ws[CV_OFF + e] -= __logf(L);
}

// ---- kernel 3: fused per-pixel output for both streams ----
__global__ void k3_out(const float* __restrict__ x1, const float* __restrict__ x2,
                       const float* __restrict__ ws,
                       const float* __restrict__ Wc1, const float* __restrict__ bc1,
                       const float* __restrict__ Wc2, const float* __restrict__ bc2,
                       const float* __restrict__ bv1, const float* __restrict__ bv2,
                       const float* __restrict__ g1p, const float* __restrict__ g2p,
                       float* __restrict__ out) {
  int b = blockIdx.x / 225;
  int n = (blockIdx.x % 225) * 256 + threadIdx.x;
  const float* At1 = ws + AT_OFF + b * 512;
  const float* At2 = ws + AT_OFF + 8192 + b * 512;
  const float* cv1 = ws + CV_OFF + b * 16;          // already includes -ln L1
  const float* cv2 = ws + CV_OFF + 256 + b * 16;    // already includes -ln L2
  const float* Wv1T = ws + WVT_OFF;
  const float* Wv2T = ws + WVT_OFF + 512;
  float g1 = g1p[0], g2 = g2p[0];
  const float* x1b = x1 + (size_t)b * 32 * HW + n;
  const float* x2b = x2 + (size_t)b * 32 * HW + n;
  float xa[32], xb[32];
  #pragma unroll
  for (int i = 0; i < 32; ++i) xa[i] = x1b[(size_t)i * HW];
  #pragma unroll
  for (int i = 0; i < 32; ++i) xb[i] = x2b[(size_t)i * HW];

  float sc[16], vv[16], o16[16];
  // ---- stream 1: attn2 = softmax(q1·k2) over x2; out1 = Wc2·(v1(x1) ⊙ attn2) ----
  #pragma unroll
  for (int t = 0; t < 16; ++t) { sc[t] = cv1[t]; vv[t] = bv1[t]; }
  #pragma unroll
  for (int i = 0; i < 32; ++i) {
    float a = xa[i], bx = xb[i];
    #pragma unroll
    for (int t = 0; t < 16; ++t) {
      sc[t] += At1[i * 16 + t] * bx;
      vv[t] += Wv1T[i * 16 + t] * a;
    }
  }
  #pragma unroll
  for (int t = 0; t < 16; ++t) o16[t] = vv[t] * __expf(sc[t]);
  float* out1 = out + (size_t)b * 32 * HW + n;
  #pragma unroll
  for (int o = 0; o < 32; ++o) {
    float acc = bc2[o];
    #pragma unroll
    for (int t = 0; t < 16; ++t) acc += Wc2[o * 16 + t] * o16[t];
    out1[(size_t)o * HW] = xa[o] + g1 * acc;
  }
  // ---- stream 2: attn1 = softmax(q2·k1) over x1; out2 = Wc1·(v2(x2) ⊙ attn1) ----
  #pragma unroll
  for (int t = 0; t < 16; ++t) { sc[t] = cv2[t]; vv[t] = bv2[t]; }
  #pragma unroll
  for (int i = 0; i < 32; ++i) {
    float a = xa[i], bx = xb[i];
    #pragma unroll
    for (int t = 0; t < 16; ++t) {
      sc[t] += At2[i * 16 + t] * a;
      vv[t] += Wv2T[i * 16 + t] * bx;
    }
  }
  #pragma unroll
  for (int t = 0; t < 16; ++t) o16[t] = vv[t] * __expf(sc[t]);
  float* out2 = out + (size_t)(BATCH * 32) * HW + (size_t)b * 32 * HW + n;
  #pragma unroll
  for (int o = 0; o < 32; ++o) {
    float acc = bc1[o];
    #pragma unroll
    for (int t = 0; t < 16; ++t) acc += Wc1[o * 16 + t] * o16[t];
    out2[(size_t)o * HW] = xb[o] + g2 * acc;
  }
}

extern "C" void kernel_launch(void* const* d_in, const int* in_sizes, int n_in,
                              void* d_out, int out_size, void* d_ws, size_t ws_size,
                              hipStream_t stream) {
  const float* x1  = (const float*)d_in[0];
  const float* x2  = (const float*)d_in[1];
  const float* Wq1 = (const float*)d_in[2];  const float* bq1 = (const float*)d_in[3];
  const float* Wk1 = (const float*)d_in[4];  const float* bk1 = (const float*)d_in[5];
  const float* Wv1 = (const float*)d_in[6];  const float* bv1 = (const float*)d_in[7];
  const float* Wq2 = (const float*)d_in[8];  const float* bq2 = (const float*)d_in[9];
  const float* Wk2 = (const float*)d_in[10]; const float* bk2 = (const float*)d_in[11];
  const float* Wv2 = (const float*)d_in[12]; const float* bv2 = (const float*)d_in[13];
  const float* Wc1 = (const float*)d_in[14]; const float* bc1 = (const float*)d_in[15];
  const float* Wc2 = (const float*)d_in[16]; const float* bc2 = (const float*)d_in[17];
  const float* g1  = (const float*)d_in[18]; const float* g2  = (const float*)d_in[19];
  float* out = (float*)d_out;
  float* ws  = (float*)d_ws;

  hipMemsetAsync(d_ws, 0, 512 * sizeof(float), stream);           // zero L accumulators
  k1a_pool<<<4096, 256, 0, stream>>>(x1, x2, ws);
  k1b_fold<<<32, 256, 0, stream>>>(ws, Wq1, bq1, Wq2, bq2, Wk1, bk1, Wk2, bk2, Wv1, Wv2);
  k2_sumexp<<<512, 256, 0, stream>>>(x1, x2, ws);
  k2b_log<<<1, 512, 0, stream>>>(ws);
  k3_out<<<3600, 256, 0, stream>>>(x1, x2, ws, Wc1, bc1, Wc2, bc2, bv1, bv2, g1, g2, out);
}